// Round 1
// baseline (576.539 us; speedup 1.0000x reference)
//
#include <hip/hip_runtime.h>
#include <hip/hip_fp16.h>

// GDE func: out = MLP(relu(mean_agg(z,edges)@Wg + z@Ws + bg))
// fp32 gather/scatter + fp16 MFMA GEMMs (threshold 3.25e-2 permits 16-bit compute;
// fp16 chosen over bf16 for 8x accuracy headroom at identical MFMA rate).

typedef _Float16 f16;
typedef __attribute__((ext_vector_type(8))) _Float16 f16x8;
typedef __attribute__((ext_vector_type(4))) float f32x4;

__device__ __forceinline__ float fast_tanh(float x) {
  // tanh(|x|) = (1 - e^-2|x|) / (1 + e^-2|x|); ~1e-6 rel err, way under tolerance
  float a = fabsf(x);
  float e = __expf(-2.0f * a);
  float r = (1.0f - e) * __builtin_amdgcn_rcpf(1.0f + e);
  return copysignf(r, x);
}

__global__ __launch_bounds__(256) void zero_kernel(float* __restrict__ p, int n) {
  int i = blockIdx.x * 256 + threadIdx.x;
  int stride = gridDim.x * 256;
  for (; i < n; i += stride) p[i] = 0.0f;
}

// one edge per 32-lane half... quarter-group: lanes cover D=128 in 4 strided steps (coalesced)
__global__ __launch_bounds__(256) void scatter_kernel(
    const int* __restrict__ src, const int* __restrict__ dst,
    const float* __restrict__ z, float* __restrict__ agg,
    float* __restrict__ deg, int E) {
  long long t = (long long)blockIdx.x * 256 + threadIdx.x;
  int e = (int)(t >> 5);
  if (e >= E) return;
  int lane = (int)(t & 31);
  int s = src[e], d = dst[e];
  const float* zr = z + (long long)s * 128 + lane;
  float* ar = agg + (long long)d * 128 + lane;
#pragma unroll
  for (int j = 0; j < 4; ++j) atomicAdd(ar + 32 * j, zr[32 * j]);
  if (lane == 0) atomicAdd(deg + d, 1.0f);
}

// Xcat[n] = [ agg[n]/max(deg,1) (128) | z[n] (128) ]  as f16  -> one K=256 GEMM for stage 1
__global__ __launch_bounds__(256) void build_xcat(
    const float* __restrict__ agg, const float* __restrict__ deg,
    const float* __restrict__ z, f16* __restrict__ Xc, int total) {
  int i = blockIdx.x * 256 + threadIdx.x;
  int stride = gridDim.x * 256;
  for (; i < total; i += stride) {
    int n = i >> 7, d = i & 127;
    float dg = fmaxf(deg[n], 1.0f);
    Xc[(long long)n * 256 + d] = (f16)(agg[i] / dg);
    Xc[(long long)n * 256 + 128 + d] = (f16)z[i];
  }
}

// Wt[n][k] over K=256 where k<128 -> Wg[k][n], else Ws[k-128][n]
__global__ __launch_bounds__(256) void build_wgs(
    const float* __restrict__ Wg, const float* __restrict__ Ws, f16* __restrict__ Wt) {
  int i = blockIdx.x * 256 + threadIdx.x;
  if (i >= 128 * 256) return;
  int n = i >> 8, k = i & 255;
  float v = (k < 128) ? Wg[k * 128 + n] : Ws[(k - 128) * 128 + n];
  Wt[i] = (f16)v;
}

// Wt[n*K+k] = W[k*N+n]  (W is K x N row-major)
__global__ __launch_bounds__(256) void transpose_cast(
    const float* __restrict__ W, f16* __restrict__ Wt, int K, int N) {
  int i = blockIdx.x * 256 + threadIdx.x;
  if (i >= K * N) return;
  int n = i / K, k = i - n * K;
  Wt[i] = (f16)W[k * N + n];
}

// ---------------- MFMA GEMM ----------------
// C[M,NOUT] = act(X[M,K] @ W[K,NOUT] + bias), W given transposed as Wt[NOUT,K].
// 64x64 block tile, BK=64, 4 waves (2x2), each wave 32x32 = 2x2 fragments of 16x16x32.
// A-frag: lane l holds X[row=l&15][k=(l>>4)*8 + i] (8 contiguous k -> ds_read_b128)
// B-frag: lane l holds Wt[col=l&15][k=(l>>4)*8 + i]
// D-frag: lane l, reg r -> D[row=(l>>4)*4 + r][col=l&15]   (m89-verified layout)
// ACT: 0=none 1=relu 2=tanh
template <int K, int NOUT, int ACT, bool OUTF32>
__global__ __launch_bounds__(256) void gemm_kernel(
    const f16* __restrict__ X, const f16* __restrict__ Wt,
    const float* __restrict__ bias, void* __restrict__ OutV, int M) {
  constexpr int LDP = 64 + 8;  // +8 f16 = 16B pad -> 2-way (free) LDS conflicts
  __shared__ __align__(16) f16 Xs[64][LDP];
  __shared__ __align__(16) f16 Wsh[64][LDP];

  const int tid = threadIdx.x;
  const int m0 = blockIdx.x * 64;
  const int n0 = blockIdx.y * 64;
  const int wid = tid >> 6;
  const int lane = tid & 63;
  const int wm = wid & 1, wn = wid >> 1;
  const int lr = lane & 15;
  const int lk = (lane >> 4) * 8;

  f32x4 acc[2][2];
#pragma unroll
  for (int a = 0; a < 2; ++a)
#pragma unroll
    for (int b = 0; b < 2; ++b)
#pragma unroll
      for (int r = 0; r < 4; ++r) acc[a][b][r] = 0.0f;

  const int srow = tid >> 3;        // 0..31, two passes -> 64 rows
  const int scol = (tid & 7) * 8;   // 8 f16 = 16B per thread

  for (int k0 = 0; k0 < K; k0 += 64) {
#pragma unroll
    for (int p = 0; p < 2; ++p) {
      int row = srow + p * 32;
      f16x8 v;
      if (m0 + row < M) {
        v = *reinterpret_cast<const f16x8*>(X + (long long)(m0 + row) * K + k0 + scol);
      } else {
#pragma unroll
        for (int q = 0; q < 8; ++q) v[q] = (f16)0.0f;
      }
      *reinterpret_cast<f16x8*>(&Xs[row][scol]) = v;
      f16x8 w = *reinterpret_cast<const f16x8*>(Wt + (long long)(n0 + row) * K + k0 + scol);
      *reinterpret_cast<f16x8*>(&Wsh[row][scol]) = w;
    }
    __syncthreads();
#pragma unroll
    for (int kk = 0; kk < 64; kk += 32) {
      f16x8 a0 = *reinterpret_cast<const f16x8*>(&Xs[wm * 32 + lr][kk + lk]);
      f16x8 a1 = *reinterpret_cast<const f16x8*>(&Xs[wm * 32 + 16 + lr][kk + lk]);
      f16x8 b0 = *reinterpret_cast<const f16x8*>(&Wsh[wn * 32 + lr][kk + lk]);
      f16x8 b1 = *reinterpret_cast<const f16x8*>(&Wsh[wn * 32 + 16 + lr][kk + lk]);
      acc[0][0] = __builtin_amdgcn_mfma_f32_16x16x32_f16(a0, b0, acc[0][0], 0, 0, 0);
      acc[0][1] = __builtin_amdgcn_mfma_f32_16x16x32_f16(a0, b1, acc[0][1], 0, 0, 0);
      acc[1][0] = __builtin_amdgcn_mfma_f32_16x16x32_f16(a1, b0, acc[1][0], 0, 0, 0);
      acc[1][1] = __builtin_amdgcn_mfma_f32_16x16x32_f16(a1, b1, acc[1][1], 0, 0, 0);
    }
    __syncthreads();
  }

#pragma unroll
  for (int mi = 0; mi < 2; ++mi) {
#pragma unroll
    for (int ni = 0; ni < 2; ++ni) {
      int col = n0 + wn * 32 + ni * 16 + lr;
      float bv = bias[col];
#pragma unroll
      for (int r = 0; r < 4; ++r) {
        int row = m0 + wm * 32 + mi * 16 + (lane >> 4) * 4 + r;
        if (row < M) {
          float v = acc[mi][ni][r] + bv;
          if (ACT == 1) v = fmaxf(v, 0.0f);
          else if (ACT == 2) v = fast_tanh(v);
          if constexpr (OUTF32)
            ((float*)OutV)[(long long)row * NOUT + col] = v;
          else
            ((f16*)OutV)[(long long)row * NOUT + col] = (f16)v;
        }
      }
    }
  }
}

extern "C" void kernel_launch(void* const* d_in, const int* in_sizes, int n_in,
                              void* d_out, int out_size, void* d_ws, size_t ws_size,
                              hipStream_t stream) {
  const float* z  = (const float*)d_in[0];
  const int*   ei = (const int*)d_in[1];
  const float* Wg = (const float*)d_in[2];
  const float* Ws = (const float*)d_in[3];
  const float* bg = (const float*)d_in[4];
  const float* W1 = (const float*)d_in[5];
  const float* b1 = (const float*)d_in[6];
  const float* W2 = (const float*)d_in[7];
  const float* b2 = (const float*)d_in[8];
  const float* W3 = (const float*)d_in[9];
  const float* b3 = (const float*)d_in[10];

  const int Nn = in_sizes[0] / 128;
  const int E  = in_sizes[1] / 2;
  const int* src = ei;
  const int* dst = ei + E;

  // workspace layout (h2 overlays agg+Xc, both dead before stage-3 writes h2)
  char* base = (char*)d_ws;
  size_t off = 0;
  auto alloc = [&](size_t b) -> void* {
    void* p = base + off;
    off += (b + 4095) & ~(size_t)4095;
    return p;
  };
  float* agg = (float*)alloc((size_t)Nn * 128 * 4);  // 51.2 MB
  f16*   Xc  = (f16*)alloc((size_t)Nn * 256 * 2);    // 51.2 MB
  float* deg = (float*)alloc((size_t)Nn * 4);
  f16*   h1  = (f16*)alloc((size_t)Nn * 128 * 2);
  f16*   h3  = (f16*)alloc((size_t)Nn * 512 * 2);
  f16*   wgs = (f16*)alloc((size_t)128 * 256 * 2);
  f16*   wt1 = (f16*)alloc((size_t)512 * 128 * 2);
  f16*   wt2 = (f16*)alloc((size_t)512 * 512 * 2);
  f16*   wt3 = (f16*)alloc((size_t)128 * 512 * 2);
  f16*   h2  = (f16*)base;  // Nn*512*2 = 102.4 MB over agg(51.2)+Xc(51.2)

  zero_kernel<<<2048, 256, 0, stream>>>(agg, Nn * 128);
  zero_kernel<<<(Nn + 255) / 256, 256, 0, stream>>>(deg, Nn);

  build_wgs<<<(128 * 256 + 255) / 256, 256, 0, stream>>>(Wg, Ws, wgs);
  transpose_cast<<<(128 * 512 + 255) / 256, 256, 0, stream>>>(W1, wt1, 128, 512);
  transpose_cast<<<(512 * 512 + 255) / 256, 256, 0, stream>>>(W2, wt2, 512, 512);
  transpose_cast<<<(512 * 128 + 255) / 256, 256, 0, stream>>>(W3, wt3, 512, 128);

  {
    long long tot = (long long)E * 32;
    int blocks = (int)((tot + 255) / 256);
    scatter_kernel<<<blocks, 256, 0, stream>>>(src, dst, z, agg, deg, E);
  }
  build_xcat<<<2048, 256, 0, stream>>>(agg, deg, z, Xc, Nn * 128);

  int gm = (Nn + 63) / 64;
  gemm_kernel<256, 128, 1, false><<<dim3(gm, 2), 256, 0, stream>>>(Xc, wgs, bg, (void*)h1, Nn);
  gemm_kernel<128, 512, 2, false><<<dim3(gm, 8), 256, 0, stream>>>(h1, wt1, b1, (void*)h2, Nn);
  gemm_kernel<512, 512, 2, false><<<dim3(gm, 8), 256, 0, stream>>>(h2, wt2, b2, (void*)h3, Nn);
  gemm_kernel<512, 128, 0, true><<<dim3(gm, 2), 256, 0, stream>>>(h3, wt3, b3, d_out, Nn);
}

// Round 2
// 434.720 us; speedup vs baseline: 1.3262x; 1.3262x over previous
//
#include <hip/hip_runtime.h>
#include <hip/hip_fp16.h>

// GDE func: out = MLP(relu(mean_agg(z,edges)@Wg + z@Ss + bg))
// Round 1 -> 2 change: push-scatter atomics (270us, L2-thrash-bound) replaced by
// CSR build + pull gather fused with Xcat build. GEMMs unchanged (fp16 MFMA).

typedef _Float16 f16;
typedef __attribute__((ext_vector_type(8))) _Float16 f16x8;
typedef __attribute__((ext_vector_type(4))) float f32x4;

__device__ __forceinline__ float fast_tanh(float x) {
  float a = fabsf(x);
  float e = __expf(-2.0f * a);
  float r = (1.0f - e) * __builtin_amdgcn_rcpf(1.0f + e);
  return copysignf(r, x);
}

__global__ __launch_bounds__(256) void zero_kernel(int* __restrict__ p, int n) {
  int i = blockIdx.x * 256 + threadIdx.x;
  int stride = gridDim.x * 256;
  for (; i < n; i += stride) p[i] = 0;
}

// ---- CSR build ----
__global__ __launch_bounds__(256) void deg_count(const int* __restrict__ dst,
                                                 int* __restrict__ degi, int E) {
  int e = blockIdx.x * 256 + threadIdx.x;
  if (e < E) atomicAdd(&degi[dst[e]], 1);
}

// per-block (1024 elems) partial sums
__global__ __launch_bounds__(256) void scan_partial(const int* __restrict__ degi,
                                                    int* __restrict__ bsum, int N) {
  __shared__ int lds[256];
  int b = blockIdx.x, t = threadIdx.x;
  int s = 0;
#pragma unroll
  for (int j = 0; j < 4; ++j) {
    int idx = b * 1024 + t * 4 + j;
    if (idx < N) s += degi[idx];
  }
  lds[t] = s;
  __syncthreads();
  for (int off = 128; off > 0; off >>= 1) {
    if (t < off) lds[t] += lds[t + off];
    __syncthreads();
  }
  if (t == 0) bsum[b] = lds[0];
}

// serial scan of block sums (nb ~ 98, negligible); also writes row_start[N]=E
__global__ void scan_bsums(const int* __restrict__ bsum, int* __restrict__ boff,
                           int* __restrict__ row_start, int nb, int N) {
  if (threadIdx.x == 0 && blockIdx.x == 0) {
    int acc = 0;
    for (int i = 0; i < nb; ++i) { boff[i] = acc; acc += bsum[i]; }
    row_start[N] = acc;  // == E
  }
}

__global__ __launch_bounds__(256) void scan_final(
    const int* __restrict__ degi, const int* __restrict__ boff,
    int* __restrict__ row_start, int* __restrict__ cursor, int N) {
  __shared__ int lds[256];
  int b = blockIdx.x, t = threadIdx.x;
  int base = b * 1024;
  int v[4];
  int s = 0;
#pragma unroll
  for (int j = 0; j < 4; ++j) {
    int idx = base + t * 4 + j;
    v[j] = (idx < N) ? degi[idx] : 0;
    s += v[j];
  }
  lds[t] = s;
  __syncthreads();
  // Hillis-Steele inclusive scan over 256 entries
  for (int off = 1; off < 256; off <<= 1) {
    int x = lds[t];
    int y = (t >= off) ? lds[t - off] : 0;
    __syncthreads();
    lds[t] = x + y;
    __syncthreads();
  }
  int pre = boff[b] + lds[t] - s;  // exclusive prefix for this thread's 4 elems
#pragma unroll
  for (int j = 0; j < 4; ++j) {
    int idx = base + t * 4 + j;
    if (idx < N) { row_start[idx] = pre; cursor[idx] = pre; pre += v[j]; }
  }
}

__global__ __launch_bounds__(256) void fill_adj(const int* __restrict__ src,
                                                const int* __restrict__ dst,
                                                int* __restrict__ cursor,
                                                int* __restrict__ adj, int E) {
  int e = blockIdx.x * 256 + threadIdx.x;
  if (e >= E) return;
  int p = atomicAdd(&cursor[dst[e]], 1);
  adj[p] = src[e];
}

// ---- fused gather + mean + Xcat build: one 64-lane wave per node ----
// Xc[n] = [ mean_{s in adj(n)} z[s] (128, f16) | z[n] (128, f16) ]
__global__ __launch_bounds__(256) void gather_xcat(
    const float* __restrict__ z, const int* __restrict__ row_start,
    const int* __restrict__ adj, f16* __restrict__ Xc, int N) {
  int wave = (blockIdx.x * 256 + threadIdx.x) >> 6;
  int lane = threadIdx.x & 63;
  if (wave >= N) return;
  int n = wave;
  int beg = row_start[n], end = row_start[n + 1];
  float a0 = 0.0f, a1 = 0.0f;
  for (int i = beg; i < end; ++i) {
    int s = adj[i];
    const float* zp = z + (long long)s * 128;
    a0 += zp[lane];
    a1 += zp[lane + 64];
  }
  int dg = end - beg;
  float inv = 1.0f / (float)(dg > 1 ? dg : 1);
  long long o = (long long)n * 256;
  Xc[o + lane] = (f16)(a0 * inv);
  Xc[o + 64 + lane] = (f16)(a1 * inv);
  const float* zn = z + (long long)n * 128;
  Xc[o + 128 + lane] = (f16)zn[lane];
  Xc[o + 192 + lane] = (f16)zn[lane + 64];
}

// ---- weight prep ----
__global__ __launch_bounds__(256) void build_wgs(
    const float* __restrict__ Wg, const float* __restrict__ Ws, f16* __restrict__ Wt) {
  int i = blockIdx.x * 256 + threadIdx.x;
  if (i >= 128 * 256) return;
  int n = i >> 8, k = i & 255;
  float v = (k < 128) ? Wg[k * 128 + n] : Ws[(k - 128) * 128 + n];
  Wt[i] = (f16)v;
}

__global__ __launch_bounds__(256) void transpose_cast(
    const float* __restrict__ W, f16* __restrict__ Wt, int K, int N) {
  int i = blockIdx.x * 256 + threadIdx.x;
  if (i >= K * N) return;
  int n = i / K, k = i - n * K;
  Wt[i] = (f16)W[k * N + n];
}

// ---------------- MFMA GEMM (unchanged from round 1) ----------------
template <int K, int NOUT, int ACT, bool OUTF32>
__global__ __launch_bounds__(256) void gemm_kernel(
    const f16* __restrict__ X, const f16* __restrict__ Wt,
    const float* __restrict__ bias, void* __restrict__ OutV, int M) {
  constexpr int LDP = 64 + 8;
  __shared__ __align__(16) f16 Xs[64][LDP];
  __shared__ __align__(16) f16 Wsh[64][LDP];

  const int tid = threadIdx.x;
  const int m0 = blockIdx.x * 64;
  const int n0 = blockIdx.y * 64;
  const int wid = tid >> 6;
  const int lane = tid & 63;
  const int wm = wid & 1, wn = wid >> 1;
  const int lr = lane & 15;
  const int lk = (lane >> 4) * 8;

  f32x4 acc[2][2];
#pragma unroll
  for (int a = 0; a < 2; ++a)
#pragma unroll
    for (int b = 0; b < 2; ++b)
#pragma unroll
      for (int r = 0; r < 4; ++r) acc[a][b][r] = 0.0f;

  const int srow = tid >> 3;
  const int scol = (tid & 7) * 8;

  for (int k0 = 0; k0 < K; k0 += 64) {
#pragma unroll
    for (int p = 0; p < 2; ++p) {
      int row = srow + p * 32;
      f16x8 v;
      if (m0 + row < M) {
        v = *reinterpret_cast<const f16x8*>(X + (long long)(m0 + row) * K + k0 + scol);
      } else {
#pragma unroll
        for (int q = 0; q < 8; ++q) v[q] = (f16)0.0f;
      }
      *reinterpret_cast<f16x8*>(&Xs[row][scol]) = v;
      f16x8 w = *reinterpret_cast<const f16x8*>(Wt + (long long)(n0 + row) * K + k0 + scol);
      *reinterpret_cast<f16x8*>(&Wsh[row][scol]) = w;
    }
    __syncthreads();
#pragma unroll
    for (int kk = 0; kk < 64; kk += 32) {
      f16x8 a0 = *reinterpret_cast<const f16x8*>(&Xs[wm * 32 + lr][kk + lk]);
      f16x8 a1 = *reinterpret_cast<const f16x8*>(&Xs[wm * 32 + 16 + lr][kk + lk]);
      f16x8 b0 = *reinterpret_cast<const f16x8*>(&Wsh[wn * 32 + lr][kk + lk]);
      f16x8 b1 = *reinterpret_cast<const f16x8*>(&Wsh[wn * 32 + 16 + lr][kk + lk]);
      acc[0][0] = __builtin_amdgcn_mfma_f32_16x16x32_f16(a0, b0, acc[0][0], 0, 0, 0);
      acc[0][1] = __builtin_amdgcn_mfma_f32_16x16x32_f16(a0, b1, acc[0][1], 0, 0, 0);
      acc[1][0] = __builtin_amdgcn_mfma_f32_16x16x32_f16(a1, b0, acc[1][0], 0, 0, 0);
      acc[1][1] = __builtin_amdgcn_mfma_f32_16x16x32_f16(a1, b1, acc[1][1], 0, 0, 0);
    }
    __syncthreads();
  }

#pragma unroll
  for (int mi = 0; mi < 2; ++mi) {
#pragma unroll
    for (int ni = 0; ni < 2; ++ni) {
      int col = n0 + wn * 32 + ni * 16 + lr;
      float bv = bias[col];
#pragma unroll
      for (int r = 0; r < 4; ++r) {
        int row = m0 + wm * 32 + mi * 16 + (lane >> 4) * 4 + r;
        if (row < M) {
          float v = acc[mi][ni][r] + bv;
          if (ACT == 1) v = fmaxf(v, 0.0f);
          else if (ACT == 2) v = fast_tanh(v);
          if constexpr (OUTF32)
            ((float*)OutV)[(long long)row * NOUT + col] = v;
          else
            ((f16*)OutV)[(long long)row * NOUT + col] = (f16)v;
        }
      }
    }
  }
}

extern "C" void kernel_launch(void* const* d_in, const int* in_sizes, int n_in,
                              void* d_out, int out_size, void* d_ws, size_t ws_size,
                              hipStream_t stream) {
  const float* z  = (const float*)d_in[0];
  const int*   ei = (const int*)d_in[1];
  const float* Wg = (const float*)d_in[2];
  const float* Ws = (const float*)d_in[3];
  const float* bg = (const float*)d_in[4];
  const float* W1 = (const float*)d_in[5];
  const float* b1 = (const float*)d_in[6];
  const float* W2 = (const float*)d_in[7];
  const float* b2 = (const float*)d_in[8];
  const float* W3 = (const float*)d_in[9];
  const float* b3 = (const float*)d_in[10];

  const int Nn = in_sizes[0] / 128;
  const int E  = in_sizes[1] / 2;
  const int* src = ei;
  const int* dst = ei + E;
  const int nb = (Nn + 1023) / 1024;

  // workspace layout (explicit byte offsets, peak ~231.3 MB):
  //   [0, XCB)            Xc      (dead after GEMM1)
  //   [XCB, XCB+~3.6MB)   CSR arrays (dead after gather)
  //   [0, H2B)            h2      (overlays Xc+CSR; written by GEMM2)
  //   [H2B, +25.6MB)      h1
  //   [..., +102.4MB)     h3
  //   [...]               prepped weights
  char* base = (char*)d_ws;
  const size_t XCB = (size_t)Nn * 256 * 2;   // 51.2 MB
  const size_t H2B = (size_t)Nn * 512 * 2;   // 102.4 MB
  f16* Xc = (f16*)(base);
  f16* h2 = (f16*)(base);
  size_t off = XCB;
  auto alloc = [&](size_t b) -> void* {
    void* p = base + off;
    off += (b + 255) & ~(size_t)255;
    return p;
  };
  int* degi      = (int*)alloc((size_t)Nn * 4);
  int* row_start = (int*)alloc((size_t)(Nn + 1) * 4);
  int* cursor    = (int*)alloc((size_t)Nn * 4);
  int* adj       = (int*)alloc((size_t)E * 4);
  int* bsum      = (int*)alloc((size_t)nb * 4);
  int* boff      = (int*)alloc((size_t)nb * 4);
  off = H2B;  // jump past h2 overlay span
  f16* h1  = (f16*)alloc((size_t)Nn * 128 * 2);
  f16* h3  = (f16*)alloc((size_t)Nn * 512 * 2);
  f16* wgs = (f16*)alloc((size_t)128 * 256 * 2);
  f16* wt1 = (f16*)alloc((size_t)512 * 128 * 2);
  f16* wt2 = (f16*)alloc((size_t)512 * 512 * 2);
  f16* wt3 = (f16*)alloc((size_t)128 * 512 * 2);

  // CSR build
  zero_kernel<<<(Nn + 255) / 256, 256, 0, stream>>>(degi, Nn);
  deg_count<<<(E + 255) / 256, 256, 0, stream>>>(dst, degi, E);
  scan_partial<<<nb, 256, 0, stream>>>(degi, bsum, Nn);
  scan_bsums<<<1, 64, 0, stream>>>(bsum, boff, row_start, nb, Nn);
  scan_final<<<nb, 256, 0, stream>>>(degi, boff, row_start, cursor, Nn);
  fill_adj<<<(E + 255) / 256, 256, 0, stream>>>(src, dst, cursor, adj, E);

  // weight prep (independent; scheduler may overlap)
  build_wgs<<<(128 * 256 + 255) / 256, 256, 0, stream>>>(Wg, Ws, wgs);
  transpose_cast<<<(128 * 512 + 255) / 256, 256, 0, stream>>>(W1, wt1, 128, 512);
  transpose_cast<<<(512 * 512 + 255) / 256, 256, 0, stream>>>(W2, wt2, 512, 512);
  transpose_cast<<<(512 * 128 + 255) / 256, 256, 0, stream>>>(W3, wt3, 512, 128);

  // fused gather + mean + Xcat
  {
    long long tot = (long long)Nn * 64;
    gather_xcat<<<(int)((tot + 255) / 256), 256, 0, stream>>>(z, row_start, adj, Xc, Nn);
  }

  int gm = (Nn + 63) / 64;
  gemm_kernel<256, 128, 1, false><<<dim3(gm, 2), 256, 0, stream>>>(Xc, wgs, bg, (void*)h1, Nn);
  gemm_kernel<128, 512, 2, false><<<dim3(gm, 8), 256, 0, stream>>>(h1, wt1, b1, (void*)h2, Nn);
  gemm_kernel<512, 512, 2, false><<<dim3(gm, 8), 256, 0, stream>>>(h2, wt2, b2, (void*)h3, Nn);
  gemm_kernel<512, 128, 0, true><<<dim3(gm, 2), 256, 0, stream>>>(h3, wt3, b3, d_out, Nn);
}

// Round 3
// 433.056 us; speedup vs baseline: 1.3313x; 1.0038x over previous
//
#include <hip/hip_runtime.h>
#include <hip/hip_fp16.h>

// GDE func: out = MLP(relu(mean_agg(z,edges)@Wg + z@Ws + bg))
// Round 2 -> 3: GEMMs moved to m97 structure (128x128 tile, BK=64,
// global_load_lds width-16 staging, 4 waves x 4x4 16x16x32 fragments).
// Activations padded to Mpad rows so staging needs no bounds checks.

typedef _Float16 f16;
typedef __attribute__((ext_vector_type(8))) _Float16 f16x8;
typedef __attribute__((ext_vector_type(4))) float f32x4;

__device__ __forceinline__ void async_load16(const void* g, void* lds) {
  __builtin_amdgcn_global_load_lds(
      (const __attribute__((address_space(1))) void*)g,
      (__attribute__((address_space(3))) void*)lds, 16, 0, 0);
}

__device__ __forceinline__ float fast_tanh(float x) {
  float a = fabsf(x);
  float e = __expf(-2.0f * a);
  float r = (1.0f - e) * __builtin_amdgcn_rcpf(1.0f + e);
  return copysignf(r, x);
}

__global__ __launch_bounds__(256) void zero_kernel(int* __restrict__ p, int n) {
  int i = blockIdx.x * 256 + threadIdx.x;
  int stride = gridDim.x * 256;
  for (; i < n; i += stride) p[i] = 0;
}

// ---- CSR build ----
__global__ __launch_bounds__(256) void deg_count(const int* __restrict__ dst,
                                                 int* __restrict__ degi, int E) {
  int e = blockIdx.x * 256 + threadIdx.x;
  if (e < E) atomicAdd(&degi[dst[e]], 1);
}

__global__ __launch_bounds__(256) void scan_partial(const int* __restrict__ degi,
                                                    int* __restrict__ bsum, int N) {
  __shared__ int lds[256];
  int b = blockIdx.x, t = threadIdx.x;
  int s = 0;
#pragma unroll
  for (int j = 0; j < 4; ++j) {
    int idx = b * 1024 + t * 4 + j;
    if (idx < N) s += degi[idx];
  }
  lds[t] = s;
  __syncthreads();
  for (int off = 128; off > 0; off >>= 1) {
    if (t < off) lds[t] += lds[t + off];
    __syncthreads();
  }
  if (t == 0) bsum[b] = lds[0];
}

__global__ void scan_bsums(const int* __restrict__ bsum, int* __restrict__ boff,
                           int* __restrict__ row_start, int nb, int N) {
  if (threadIdx.x == 0 && blockIdx.x == 0) {
    int acc = 0;
    for (int i = 0; i < nb; ++i) { boff[i] = acc; acc += bsum[i]; }
    row_start[N] = acc;  // == E
  }
}

__global__ __launch_bounds__(256) void scan_final(
    const int* __restrict__ degi, const int* __restrict__ boff,
    int* __restrict__ row_start, int* __restrict__ cursor, int N) {
  __shared__ int lds[256];
  int b = blockIdx.x, t = threadIdx.x;
  int base = b * 1024;
  int v[4];
  int s = 0;
#pragma unroll
  for (int j = 0; j < 4; ++j) {
    int idx = base + t * 4 + j;
    v[j] = (idx < N) ? degi[idx] : 0;
    s += v[j];
  }
  lds[t] = s;
  __syncthreads();
  for (int off = 1; off < 256; off <<= 1) {
    int x = lds[t];
    int y = (t >= off) ? lds[t - off] : 0;
    __syncthreads();
    lds[t] = x + y;
    __syncthreads();
  }
  int pre = boff[b] + lds[t] - s;
#pragma unroll
  for (int j = 0; j < 4; ++j) {
    int idx = base + t * 4 + j;
    if (idx < N) { row_start[idx] = pre; cursor[idx] = pre; pre += v[j]; }
  }
}

__global__ __launch_bounds__(256) void fill_adj(const int* __restrict__ src,
                                                const int* __restrict__ dst,
                                                int* __restrict__ cursor,
                                                int* __restrict__ adj, int E) {
  int e = blockIdx.x * 256 + threadIdx.x;
  if (e >= E) return;
  int p = atomicAdd(&cursor[dst[e]], 1);
  adj[p] = src[e];
}

// ---- fused gather + mean + Xcat: one 64-lane wave per node ----
__global__ __launch_bounds__(256) void gather_xcat(
    const float* __restrict__ z, const int* __restrict__ row_start,
    const int* __restrict__ adj, f16* __restrict__ Xc, int N) {
  int wave = (blockIdx.x * 256 + threadIdx.x) >> 6;
  int lane = threadIdx.x & 63;
  if (wave >= N) return;
  int n = wave;
  int beg = row_start[n], end = row_start[n + 1];
  float a0 = 0.0f, a1 = 0.0f;
  for (int i = beg; i < end; ++i) {
    int s = adj[i];
    const float* zp = z + (long long)s * 128;
    a0 += zp[lane];
    a1 += zp[lane + 64];
  }
  int dg = end - beg;
  float inv = 1.0f / (float)(dg > 1 ? dg : 1);
  long long o = (long long)n * 256;
  Xc[o + lane] = (f16)(a0 * inv);
  Xc[o + 64 + lane] = (f16)(a1 * inv);
  const float* zn = z + (long long)n * 128;
  Xc[o + 128 + lane] = (f16)zn[lane];
  Xc[o + 192 + lane] = (f16)zn[lane + 64];
}

// ---- weight prep ----
__global__ __launch_bounds__(256) void build_wgs(
    const float* __restrict__ Wg, const float* __restrict__ Ws, f16* __restrict__ Wt) {
  int i = blockIdx.x * 256 + threadIdx.x;
  if (i >= 128 * 256) return;
  int n = i >> 8, k = i & 255;
  float v = (k < 128) ? Wg[k * 128 + n] : Ws[(k - 128) * 128 + n];
  Wt[i] = (f16)v;
}

__global__ __launch_bounds__(256) void transpose_cast(
    const float* __restrict__ W, f16* __restrict__ Wt, int K, int N) {
  int i = blockIdx.x * 256 + threadIdx.x;
  if (i >= K * N) return;
  int n = i / K, k = i - n * K;
  Wt[i] = (f16)W[k * N + n];
}

// ---------------- m97-structure MFMA GEMM ----------------
// C[M,NOUT] = act(X[M,K] @ Wt^T + bias); Wt is [NOUT][K] row-major f16.
// BM=BN=128, BK=64. 256 thr = 4 waves (2x2); wave tile 64x64 = 4x4 frags.
// Staging: global_load_lds 16B/lane, chunk q=wid*4+c covers 8 rows (1 KiB).
// A-frag lane l: row (l&15), k (l>>4)*8+i ; D: row=(l>>4)*4+r, col=l&15.
// X must have >= gridDim.x*128 allocated rows (Mpad); rows >= M never stored.
template <int K, int NOUT, int ACT, bool OUTF32>
__global__ __launch_bounds__(256) void gemm128(
    const f16* __restrict__ X, const f16* __restrict__ Wt,
    const float* __restrict__ bias, void* __restrict__ OutV, int M) {
  __shared__ __align__(16) f16 Xs[128 * 64];
  __shared__ __align__(16) f16 Wsh[128 * 64];

  const int tid = threadIdx.x;
  const int wid = tid >> 6, lane = tid & 63;
  const int wm = wid & 1, wn = wid >> 1;
  const int lr = lane & 15, lk4 = lane >> 4;
  const long long m0 = (long long)blockIdx.x * 128;
  const int n0 = blockIdx.y * 128;

  f32x4 acc[4][4];
#pragma unroll
  for (int i = 0; i < 4; ++i)
#pragma unroll
    for (int j = 0; j < 4; ++j)
#pragma unroll
      for (int r = 0; r < 4; ++r) acc[i][j][r] = 0.0f;

  const int srow = lane >> 3;        // 0..7 within chunk
  const int scol = (lane & 7) * 8;   // f16 col, 16B granularity
  const f16* Xg = X + m0 * K;
  const f16* Wg = Wt + (long long)n0 * K;

  for (int k0 = 0; k0 < K; k0 += 64) {
#pragma unroll
    for (int c = 0; c < 4; ++c) {
      int q = wid * 4 + c;                 // chunk 0..15 -> rows q*8..q*8+7
      long long row = q * 8 + srow;
      async_load16(Xg + row * K + k0 + scol, &Xs[q * 512]);
      async_load16(Wg + row * K + k0 + scol, &Wsh[q * 512]);
    }
    __syncthreads();
#pragma unroll
    for (int kk = 0; kk < 64; kk += 32) {
      f16x8 a[4], b[4];
#pragma unroll
      for (int i = 0; i < 4; ++i) {
        a[i] = *reinterpret_cast<const f16x8*>(&Xs[(wm * 64 + i * 16 + lr) * 64 + kk + lk4 * 8]);
        b[i] = *reinterpret_cast<const f16x8*>(&Wsh[(wn * 64 + i * 16 + lr) * 64 + kk + lk4 * 8]);
      }
#pragma unroll
      for (int i = 0; i < 4; ++i)
#pragma unroll
        for (int j = 0; j < 4; ++j)
          acc[i][j] = __builtin_amdgcn_mfma_f32_16x16x32_f16(a[i], b[j], acc[i][j], 0, 0, 0);
    }
    __syncthreads();
  }

#pragma unroll
  for (int i = 0; i < 4; ++i) {
#pragma unroll
    for (int j = 0; j < 4; ++j) {
      int col = n0 + wn * 64 + j * 16 + lr;
      float bv = bias[col];
#pragma unroll
      for (int r = 0; r < 4; ++r) {
        long long row = m0 + wm * 64 + i * 16 + lk4 * 4 + r;
        if (row < M) {
          float v = acc[i][j][r] + bv;
          if (ACT == 1) v = fmaxf(v, 0.0f);
          else if (ACT == 2) v = fast_tanh(v);
          if constexpr (OUTF32)
            ((float*)OutV)[row * NOUT + col] = v;
          else
            ((f16*)OutV)[row * NOUT + col] = (f16)v;
        }
      }
    }
  }
}

extern "C" void kernel_launch(void* const* d_in, const int* in_sizes, int n_in,
                              void* d_out, int out_size, void* d_ws, size_t ws_size,
                              hipStream_t stream) {
  const float* z  = (const float*)d_in[0];
  const int*   ei = (const int*)d_in[1];
  const float* Wg = (const float*)d_in[2];
  const float* Ws = (const float*)d_in[3];
  const float* bg = (const float*)d_in[4];
  const float* W1 = (const float*)d_in[5];
  const float* b1 = (const float*)d_in[6];
  const float* W2 = (const float*)d_in[7];
  const float* b2 = (const float*)d_in[8];
  const float* W3 = (const float*)d_in[9];
  const float* b3 = (const float*)d_in[10];

  const int Nn = in_sizes[0] / 128;
  const int E  = in_sizes[1] / 2;
  const int* src = ei;
  const int* dst = ei + E;
  const int nb = (Nn + 1023) / 1024;
  const int gm = (Nn + 127) / 128;      // 128-row tiles
  const long long Mpad = (long long)gm * 128;

  // workspace layout (peak ~232 MB):
  //   [0, XCB)   Xc (Mpad x 256 f16)      — dead after GEMM1
  //   [XCB, ..)  CSR arrays (~3.7 MB)     — dead after gather
  //   [0, H2B)   h2 (Mpad x 512 f16)      — overlays Xc+CSR
  //   then h1, h3, prepped weights
  char* base = (char*)d_ws;
  const size_t XCB = (size_t)Mpad * 256 * 2;
  const size_t H2B = (size_t)Mpad * 512 * 2;
  f16* Xc = (f16*)(base);
  f16* h2 = (f16*)(base);
  size_t off = XCB;
  auto alloc = [&](size_t b) -> void* {
    void* p = base + off;
    off += (b + 255) & ~(size_t)255;
    return p;
  };
  int* degi      = (int*)alloc((size_t)Nn * 4);
  int* row_start = (int*)alloc((size_t)(Nn + 1) * 4);
  int* cursor    = (int*)alloc((size_t)Nn * 4);
  int* adj       = (int*)alloc((size_t)E * 4);
  int* bsum      = (int*)alloc((size_t)nb * 4);
  int* boff      = (int*)alloc((size_t)nb * 4);
  off = H2B;
  f16* h1  = (f16*)alloc((size_t)Mpad * 128 * 2);
  f16* h3  = (f16*)alloc((size_t)Mpad * 512 * 2);
  f16* wgs = (f16*)alloc((size_t)128 * 256 * 2);
  f16* wt1 = (f16*)alloc((size_t)512 * 128 * 2);
  f16* wt2 = (f16*)alloc((size_t)512 * 512 * 2);
  f16* wt3 = (f16*)alloc((size_t)128 * 512 * 2);

  // CSR build
  zero_kernel<<<(Nn + 255) / 256, 256, 0, stream>>>(degi, Nn);
  deg_count<<<(E + 255) / 256, 256, 0, stream>>>(dst, degi, E);
  scan_partial<<<nb, 256, 0, stream>>>(degi, bsum, Nn);
  scan_bsums<<<1, 64, 0, stream>>>(bsum, boff, row_start, nb, Nn);
  scan_final<<<nb, 256, 0, stream>>>(degi, boff, row_start, cursor, Nn);
  fill_adj<<<(E + 255) / 256, 256, 0, stream>>>(src, dst, cursor, adj, E);

  // weight prep
  build_wgs<<<(128 * 256 + 255) / 256, 256, 0, stream>>>(Wg, Ws, wgs);
  transpose_cast<<<(128 * 512 + 255) / 256, 256, 0, stream>>>(W1, wt1, 128, 512);
  transpose_cast<<<(512 * 512 + 255) / 256, 256, 0, stream>>>(W2, wt2, 512, 512);
  transpose_cast<<<(512 * 128 + 255) / 256, 256, 0, stream>>>(W3, wt3, 512, 128);

  // gather + Xcat
  {
    long long tot = (long long)Nn * 64;
    gather_xcat<<<(int)((tot + 255) / 256), 256, 0, stream>>>(z, row_start, adj, Xc, Nn);
  }

  gemm128<256, 128, 1, false><<<dim3(gm, 1), 256, 0, stream>>>(Xc, wgs, bg, (void*)h1, Nn);
  gemm128<128, 512, 2, false><<<dim3(gm, 4), 256, 0, stream>>>(h1, wt1, b1, (void*)h2, Nn);
  gemm128<512, 512, 2, false><<<dim3(gm, 4), 256, 0, stream>>>(h2, wt2, b2, (void*)h3, Nn);
  gemm128<512, 128, 0, true><<<dim3(gm, 1), 256, 0, stream>>>(h3, wt3, b3, d_out, Nn);
}